// Round 10
// baseline (283.540 us; speedup 1.0000x reference)
//
#include <hip/hip_runtime.h>
#include <hip/hip_bf16.h>
#include <math.h>

// Problem constants
#define T_LEN 2048
#define C_DIM 2048
#define NH 16
#define HD 128
#define RANK 64
#define W_LOCAL 512
#define QKV_LD 6144
#define ROW_BF 12288          // qkv row stride in bf16 elems
#define KB_OFF 4096           // bf16-elem offset of packed K overlay within row
#define VB_OFF 8192           // bf16-elem offset of packed V overlay within row
#define WO_OFF 6144           // bf16-elem offset of packed w_o row within qkv row
#define SCALE 0.08838834764831845f    // 1/sqrt(128)
#define SCALE_G 0.17677669529663687f  // scale * 128/64
#define LOG1E4_OVER_64 0.14391156831212787f

typedef __bf16 bf16_t;
typedef __bf16 bf16x8 __attribute__((ext_vector_type(8)));
typedef __bf16 bf16x4 __attribute__((ext_vector_type(4)));
typedef float f32x4 __attribute__((ext_vector_type(4)));

// ---------------------------------------------------------------------------
// async 16B global -> LDS (gfx950). LDS dst must be wave-uniform base+lane*16.
// ---------------------------------------------------------------------------
__device__ __forceinline__ void async_copy16(const bf16_t* g, bf16_t* l) {
    __builtin_amdgcn_global_load_lds(
        (const __attribute__((address_space(1))) unsigned int*)g,
        (__attribute__((address_space(3))) unsigned int*)l, 16, 0, 0);
}

// ---------------------------------------------------------------------------
// Merged prep kernel (block-range dispatch):
//  [0,2048):    x -> xb bf16 (hi only; info MLP re-derives lo from fp32 x)
//  [2048,8192): w_qkv -> wqb bf16
//  [8192,8704): rope tables
// ---------------------------------------------------------------------------
__global__ __launch_bounds__(256)
void prep_kernel(const float* __restrict__ x, bf16_t* __restrict__ xb,
                 const float* __restrict__ w_qkv, bf16_t* __restrict__ wqb,
                 float* __restrict__ tab) {
    const int bid = blockIdx.x;
    const int tid = threadIdx.x;
    if (bid < 2048) {
        int idx = bid * 256 + tid;                   // 8 elems each
        const float* p = x + (size_t)idx * 8;
        float4 v0 = *(const float4*)p;
        float4 v1 = *(const float4*)(p + 4);
        bf16x8 o;
        o[0] = (bf16_t)v0.x; o[1] = (bf16_t)v0.y; o[2] = (bf16_t)v0.z; o[3] = (bf16_t)v0.w;
        o[4] = (bf16_t)v1.x; o[5] = (bf16_t)v1.y; o[6] = (bf16_t)v1.z; o[7] = (bf16_t)v1.w;
        *(bf16x8*)(xb + (size_t)idx * 8) = o;
    } else if (bid < 8192) {
        // w_qkv fp32 -> bf16 (6144x2048)
        int idx = (bid - 2048) * 256 + tid;          // 8 elems each
        const float* p = w_qkv + (size_t)idx * 8;
        float4 v0 = *(const float4*)p;
        float4 v1 = *(const float4*)(p + 4);
        bf16x8 o;
        o[0] = (bf16_t)v0.x; o[1] = (bf16_t)v0.y; o[2] = (bf16_t)v0.z; o[3] = (bf16_t)v0.w;
        o[4] = (bf16_t)v1.x; o[5] = (bf16_t)v1.y; o[6] = (bf16_t)v1.z; o[7] = (bf16_t)v1.w;
        *(bf16x8*)(wqb + (size_t)idx * 8) = o;
    } else {
        // rope tables
        int idx = (bid - 8192) * 256 + tid;          // 2048*64
        int t = idx >> 6, j = idx & 63;
        float inv = expf(-(float)j * LOG1E4_OVER_64);
        float s, c;
        sincosf((float)t * inv, &s, &c);
        tab[t * 128 + j] = c;
        tab[t * 128 + 64 + j] = s;
    }
}

// ---------------------------------------------------------------------------
// MERGED dispatch: info-MLP GEMM + qkv GEMM v4 + piggy-backed w_o conversion.
//  Blocks [0,128):    info MLP split-bf16 GEMM (split-K=2), reg-staged from
//                     fp32 x/w1, partials->ipart (second half of d_out).
//  Blocks [128,896):  qkv GEMM 128x128/BK=64/2 blocks/CU, counted vmcnt,
//                     both-sides XOR swizzle, fused RoPE epilogue, V overlay
//                     + V^T (vt, first half of d_out).
//                     bn-FASTEST within XCD: B-stripe stays L2-resident.
//  Blocks [896,2944): w_o row -> bf16 WO_OFF overlay.
// ---------------------------------------------------------------------------
#define NTK 32      // 2048 / 64
#define ILD 40      // info LDS leading dim (padded: 128x40 bf16 per buffer)

#define STG_A(bb, ktile) do {                                                  \
    _Pragma("unroll")                                                          \
    for (int c_ = 0; c_ < 4; ++c_)                                             \
        async_copy16(gA + (size_t)(c_ * 32) * 2048 + (ktile) * 64,             \
                     &lds[bb][0][(c_ * 32 + rS) * 64 + dS]);                   \
} while (0)

#define STG_B(bb, ktile) do {                                                  \
    _Pragma("unroll")                                                          \
    for (int c_ = 0; c_ < 4; ++c_)                                             \
        async_copy16(gB + (size_t)(c_ * 32) * 2048 + (ktile) * 64,             \
                     &lds[bb][1][(c_ * 32 + rS) * 64 + dS]);                   \
} while (0)

#define RD_A(bb, m, k) (*(const bf16x8*)&lds[bb][0][(wr * 64 + (m) * 16 + l16) * 64 + (((k) * 4 + quad) ^ xsw) * 8])
#define RD_B(bb, n, k) (*(const bf16x8*)&lds[bb][1][(wc * 64 + (n) * 16 + l16) * 64 + (((k) * 4 + quad) ^ xsw) * 8])

__global__ __launch_bounds__(256, 2)
void gemm_qkv_rope(const bf16_t* __restrict__ A, const bf16_t* __restrict__ B,
                   bf16_t* __restrict__ qkv_bf, bf16_t* __restrict__ vt,
                   const float* __restrict__ tab, const float* __restrict__ w_o,
                   const float* __restrict__ x, const float* __restrict__ w1,
                   float* __restrict__ ipart) {
    __shared__ __align__(16) unsigned char smem[65536];
    const int bid = blockIdx.x;
    const int tid = threadIdx.x;

    if (bid < 128) {
        // ---------------- info MLP block (split-bf16, 3x MFMA) ----------------
        bf16_t* Ah = (bf16_t*)smem;            // [128][ILD]
        bf16_t* Al = Ah + 128 * ILD;
        bf16_t* Bh = Al + 128 * ILD;
        bf16_t* Bl = Bh + 128 * ILD;
        const int bn = bid & 3, bm = (bid >> 2) & 15, ks = bid >> 6;
        const int wave = tid >> 6, lane = tid & 63;
        const int quad = lane >> 4, l16 = lane & 15;
        const int wm = (wave >> 1) * 64, wn = (wave & 1) * 64;
        const int lrow = lane >> 2;
        const int lkb = (lane & 3) * 8;
        const int kbeg = ks * 1024;

        f32x4 acc[4][4];
#pragma unroll
        for (int i = 0; i < 4; ++i)
#pragma unroll
            for (int j = 0; j < 4; ++j) acc[i][j] = (f32x4){0.f, 0.f, 0.f, 0.f};

        const float* gx = x + (size_t)(bm * 128 + wave * 16 + lrow) * 2048 + kbeg + lkb;
        const float* gw = w1 + (size_t)(bn * 128 + wave * 16 + lrow) * 2048 + kbeg + lkb;
        const int wrow = (wave * 16 + lrow) * ILD + lkb;

        for (int k0 = 0; k0 < 1024; k0 += 32) {
            __syncthreads();
#pragma unroll
            for (int hr = 0; hr < 2; ++hr) {
                const float* px = gx + (size_t)hr * 64 * 2048 + k0;
                float4 a0 = *(const float4*)px, a1 = *(const float4*)(px + 4);
                float av[8] = {a0.x, a0.y, a0.z, a0.w, a1.x, a1.y, a1.z, a1.w};
                bf16x8 h, l;
#pragma unroll
                for (int i = 0; i < 8; ++i) {
                    bf16_t hb = (bf16_t)av[i];
                    h[i] = hb; l[i] = (bf16_t)(av[i] - (float)hb);
                }
                *(bf16x8*)&Ah[wrow + hr * 64 * ILD] = h;
                *(bf16x8*)&Al[wrow + hr * 64 * ILD] = l;

                const float* pw = gw + (size_t)hr * 64 * 2048 + k0;
                float4 b0 = *(const float4*)pw, b1 = *(const float4*)(pw + 4);
                float bv[8] = {b0.x, b0.y, b0.z, b0.w, b1.x, b1.y, b1.z, b1.w};
                bf16x8 hb2, lb2;
#pragma unroll
                for (int i = 0; i < 8; ++i) {
                    bf16_t hh = (bf16_t)bv[i];
                    hb2[i] = hh; lb2[i] = (bf16_t)(bv[i] - (float)hh);
                }
                *(bf16x8*)&Bh[wrow + hr * 64 * ILD] = hb2;
                *(bf16x8*)&Bl[wrow + hr * 64 * ILD] = lb2;
            }
            __syncthreads();

            bf16x8 ah[4], al[4], bh[4], bl[4];
#pragma unroll
            for (int mt = 0; mt < 4; ++mt) {
                ah[mt] = *(const bf16x8*)&Ah[(wm + mt * 16 + l16) * ILD + quad * 8];
                al[mt] = *(const bf16x8*)&Al[(wm + mt * 16 + l16) * ILD + quad * 8];
            }
#pragma unroll
            for (int nt = 0; nt < 4; ++nt) {
                bh[nt] = *(const bf16x8*)&Bh[(wn + nt * 16 + l16) * ILD + quad * 8];
                bl[nt] = *(const bf16x8*)&Bl[(wn + nt * 16 + l16) * ILD + quad * 8];
            }
#pragma unroll
            for (int mt = 0; mt < 4; ++mt)
#pragma unroll
                for (int nt = 0; nt < 4; ++nt) {
                    acc[mt][nt] = __builtin_amdgcn_mfma_f32_16x16x32_bf16(ah[mt], bh[nt], acc[mt][nt], 0, 0, 0);
                    acc[mt][nt] = __builtin_amdgcn_mfma_f32_16x16x32_bf16(ah[mt], bl[nt], acc[mt][nt], 0, 0, 0);
                    acc[mt][nt] = __builtin_amdgcn_mfma_f32_16x16x32_bf16(al[mt], bh[nt], acc[mt][nt], 0, 0, 0);
                }
        }

        float* cp = ipart + (size_t)ks * 2048 * 512;
#pragma unroll
        for (int mt = 0; mt < 4; ++mt)
#pragma unroll
            for (int r = 0; r < 4; ++r) {
                int row = bm * 128 + wm + mt * 16 + quad * 4 + r;
                float* crow = cp + (size_t)row * 512 + bn * 128 + wn;
#pragma unroll
                for (int nt = 0; nt < 4; ++nt)
                    crow[nt * 16 + l16] = acc[mt][nt][r];
            }
        return;
    }

    if (bid >= 896) {
        // ---------------- w_o conversion: one row per block ----------------
        int row = bid - 896;
        int c = tid * 8;
        const float* p = w_o + (size_t)row * 2048 + c;
        float4 v0 = *(const float4*)p;
        float4 v1 = *(const float4*)(p + 4);
        bf16x8 o;
        o[0] = (bf16_t)v0.x; o[1] = (bf16_t)v0.y; o[2] = (bf16_t)v0.z; o[3] = (bf16_t)v0.w;
        o[4] = (bf16_t)v1.x; o[5] = (bf16_t)v1.y; o[6] = (bf16_t)v1.z; o[7] = (bf16_t)v1.w;
        *(bf16x8*)(qkv_bf + (size_t)row * ROW_BF + WO_OFF + c) = o;
        return;
    }

    // ---------------- qkv GEMM v4 block ----------------
    typedef bf16_t ldsbuf_t[2][128 * 64];
    ldsbuf_t* lds = (ldsbuf_t*)smem;           // [2][2][8192], 64 KiB

    const int gid = bid - 128;                 // 0..767
    const int xcd = gid & 7, idx = gid >> 3;   // 96 blocks per XCD
    const int bn_ = xcd * 6 + (idx % 6);       // bn FASTEST: B-stripe L2-resident
    const int bm_ = idx / 6;                   // 0..15
    const int wave = tid >> 6, lane = tid & 63;
    const int quad = lane >> 4, l16 = lane & 15;
    const int wr = wave >> 1, wc = wave & 1;   // 2x2 wave grid, wave tile 64x64
    const int xsw = l16 & 7;

    // staging geometry: thread covers (row rS + 32*c, phys chunk tid&7);
    // global source chunk pre-swizzled: phys chunk p holds logical p^(row&7)
    const int rS = tid >> 3;                   // 0..31
    const int cS = ((tid & 7) ^ (rS & 7)) * 8; // global col (bf16)
    const int dS = (tid & 7) * 8;              // linear LDS chunk
    const bf16_t* gA = A + (size_t)(bm_ * 128 + rS) * 2048 + cS;
    const bf16_t* gB = B + (size_t)(bn_ * 128 + rS) * 2048 + cS;

    f32x4 acc[4][4];
#pragma unroll
    for (int i = 0; i < 4; ++i)
#pragma unroll
        for (int j = 0; j < 4; ++j) acc[i][j] = (f32x4){0.f, 0.f, 0.f, 0.f};

    // Prologue: stage tiles 0 and 1; wait for tile 0, leave tile 1 in flight.
    STG_A(0, 0); STG_B(0, 0);
    STG_A(1, 1); STG_B(1, 1);
    asm volatile("s_waitcnt vmcnt(8)" ::: "memory");
    __builtin_amdgcn_s_barrier();

    for (int kt = 0; kt < NTK; ++kt) {
        const int b = kt & 1;
        bf16x8 af[4][2], bfr[4][2];
#pragma unroll
        for (int m = 0; m < 4; ++m) { af[m][0] = RD_A(b, m, 0); af[m][1] = RD_A(b, m, 1); }
#pragma unroll
        for (int n = 0; n < 4; ++n) { bfr[n][0] = RD_B(b, n, 0); bfr[n][1] = RD_B(b, n, 1); }
        asm volatile("s_waitcnt lgkmcnt(0)" ::: "memory");
        __builtin_amdgcn_s_barrier();          // all waves done reading buf b

        __builtin_amdgcn_s_setprio(1);
#pragma unroll
        for (int m = 0; m < 4; ++m)
#pragma unroll
            for (int n = 0; n < 4; ++n)
                acc[m][n] = __builtin_amdgcn_mfma_f32_16x16x32_bf16(af[m][0], bfr[n][0], acc[m][n], 0, 0, 0);
        __builtin_amdgcn_s_setprio(0);
        if (kt + 2 < NTK) STG_A(b, kt + 2);    // buf b safe to overwrite now

        __builtin_amdgcn_s_setprio(1);
#pragma unroll
        for (int m = 0; m < 4; ++m)
#pragma unroll
            for (int n = 0; n < 4; ++n)
                acc[m][n] = __builtin_amdgcn_mfma_f32_16x16x32_bf16(af[m][1], bfr[n][1], acc[m][n], 0, 0, 0);
        __builtin_amdgcn_s_setprio(0);
        if (kt + 2 < NTK) STG_B(b, kt + 2);

        if (kt < NTK - 2) { asm volatile("s_waitcnt vmcnt(8)" ::: "memory"); }
        else              { asm volatile("s_waitcnt vmcnt(0)" ::: "memory"); }
        __builtin_amdgcn_s_barrier();
    }

    // ---- epilogue ----
    const int colbase = bn_ * 128 + wc * 64;
    const int region = (bn_ * 128) >> 11;      // 0=q, 1=k, 2=v (block-uniform)
    const int rowbase = bm_ * 128 + wr * 64;
    const bool odd = (l16 & 1);

    if (region == 2) {
        // (a) row-major V overlay (for kvr)
#pragma unroll
        for (int mt = 0; mt < 4; ++mt)
#pragma unroll
            for (int r = 0; r < 4; ++r) {
                int t = rowbase + mt * 16 + quad * 4 + r;
                bf16_t* brow = qkv_bf + (size_t)t * ROW_BF + VB_OFF + (colbase - 4096);
#pragma unroll
                for (int nt = 0; nt < 4; ++nt)
                    brow[nt * 16 + l16] = (bf16_t)acc[mt][nt][r];
            }
        // (b) transposed vt[h][d][t] via LDS transpose (tile = exactly one head)
        bf16_t* Tl = (bf16_t*)smem;            // [128][136] bf16, 34.8 KB
#pragma unroll
        for (int mt = 0; mt < 4; ++mt)
#pragma unroll
            for (int r = 0; r < 4; ++r) {
                int rloc = wr * 64 + mt * 16 + quad * 4 + r;
#pragma unroll
                for (int nt = 0; nt < 4; ++nt) {
                    int cloc = wc * 64 + nt * 16 + l16;
                    Tl[cloc * 136 + rloc] = (bf16_t)acc[mt][nt][r];
                }
            }
        __syncthreads();
        const int hh = bn_ - 32;               // head index
        const int d = tid >> 1, th = (tid & 1) * 64;
        bf16_t* dst = vt + ((size_t)(hh * 128 + d)) * 2048 + bm_ * 128 + th;
        const bf16_t* srcT = Tl + d * 136 + th;
#pragma unroll
        for (int j = 0; j < 8; ++j)
            *(bf16x8*)(dst + j * 8) = *(const bf16x8*)(srcT + j * 8);
    } else {
        // RoPE for q/k; store bf16 overlay (q @0, k @KB_OFF)
#pragma unroll
        for (int mt = 0; mt < 4; ++mt)
#pragma unroll
            for (int r = 0; r < 4; ++r) {
                int t = rowbase + mt * 16 + quad * 4 + r;
                const float* trow = tab + t * 128;
#pragma unroll
                for (int nt = 0; nt < 4; ++nt) {
                    float v = acc[mt][nt][r];
                    float vp = __shfl_xor(v, 1);    // pair column value
                    int col = colbase + nt * 16 + l16;
                    int j = col & 63;
                    float c = trow[j], s = trow[64 + j];
                    float y = odd ? (v * c + vp * s) : (v * c - vp * s);
                    qkv_bf[(size_t)t * ROW_BF + (region == 0 ? col : col + 2048)] = (bf16_t)y;
                }
            }
    }
}

// ---------------------------------------------------------------------------
// Final GEMM: out = ctx @ w_o^T, v4 pipeline, 128x64 tile -> 512 blocks
// (2 blocks/CU). bn-fastest within XCD (B-stripe 1 MB L2-resident).
// Counted vmcnt(6); both-sides swizzle.
// ---------------------------------------------------------------------------
#define STG_A3(bb, ktile) do {                                                 \
    _Pragma("unroll")                                                          \
    for (int c_ = 0; c_ < 4; ++c_)                                             \
        async_copy16(gA + (size_t)(c_ * 32) * 2048 + (ktile) * 64,             \
                     &ldsA[bb][(c_ * 32 + rS) * 64 + dS]);                     \
} while (0)

#define STG_B3(bb, ktile) do {                                                 \
    _Pragma("unroll")                                                          \
    for (int c_ = 0; c_ < 2; ++c_)                                             \
        async_copy16(gB + (size_t)(c_ * 32) * ROW_BF + (ktile) * 64,           \
                     &ldsB[bb][(c_ * 32 + rS) * 64 + dS]);                     \
} while (0)

#define RD_A3(bb, m, k) (*(const bf16x8*)&ldsA[bb][(wr * 64 + (m) * 16 + l16) * 64 + (((k) * 4 + quad) ^ xsw) * 8])
#define RD_B3(bb, n, k) (*(const bf16x8*)&ldsB[bb][(wc * 32 + (n) * 16 + l16) * 64 + (((k) * 4 + quad) ^ xsw) * 8])

__global__ __launch_bounds__(256, 2)
void gemm_ctx_wo(const bf16_t* __restrict__ A, const bf16_t* __restrict__ Bov,
                 float* __restrict__ C) {
    __shared__ __align__(16) bf16_t ldsA[2][128 * 64];   // 32 KiB
    __shared__ __align__(16) bf16_t ldsB[2][64 * 64];    // 16 KiB

    const int bid = blockIdx.x;                // 0..511
    const int xcd = bid & 7, idx = bid >> 3;   // 64 blocks per XCD
    const int bn_ = xcd * 4 + (idx & 3);       // bn FASTEST: B-stripe L2-resident
    const int bm_ = idx >> 2;                  // 0..15
    const int tid = threadIdx.x;
    const int wave = tid >> 6, lane = tid & 63;
    const int quad = lane >> 4, l16 = lane & 15;
    const int wr = wave >> 1, wc = wave & 1;   // wave tile 64x32
    const int xsw = l16 & 7;

    const int rS = tid >> 3;
    const int cS = ((tid & 7) ^ (rS & 7)) * 8;
    const int dS = (tid & 7) * 8;
    const bf16_t* gA = A + (size_t)(bm_ * 128 + rS) * 2048 + cS;
    const bf16_t* gB = Bov + (size_t)(bn_ * 64 + rS) * ROW_BF + cS;

    f32x4 acc[4][2];
#pragma unroll
    for (int i = 0; i < 4; ++i)
#pragma unroll
        for (int j = 0; j < 2; ++j) acc[i][j] = (f32x4){0.f, 0.f, 0.f, 0.f};

    STG_A3(0, 0); STG_B3(0, 0);
    STG_A3(1, 1); STG_B3(1, 1);
    asm volatile("s_waitcnt vmcnt(6)" ::: "memory");
    __builtin_amdgcn_s_barrier();

    for (int kt = 0; kt < NTK; ++kt) {
        const int b = kt & 1;
        bf16x8 af[4][2], bfr[2][2];
#pragma unroll
        for (int m = 0; m < 4; ++m) { af[m][0] = RD_A3(b, m, 0); af[m][1] = RD_A3(b, m, 1); }
#pragma unroll
        for (int n = 0; n < 2; ++n) { bfr[n][0] = RD_B3(b, n, 0); bfr[n][1] = RD_B3(b, n, 1); }
        asm volatile("s_waitcnt lgkmcnt(0)" ::: "memory");
        __builtin_amdgcn_s_barrier();

        __builtin_amdgcn_s_setprio(1);
#pragma unroll
        for (int m = 0; m < 4; ++m)
#pragma unroll
            for (int n = 0; n < 2; ++n)
                acc[m][n] = __builtin_amdgcn_mfma_f32_16x16x32_bf16(af[m][0], bfr[n][0], acc[m][n], 0, 0, 0);
        __builtin_amdgcn_s_setprio(0);
        if (kt + 2 < NTK) STG_A3(b, kt + 2);

        __builtin_amdgcn_s_setprio(1);
#pragma unroll
        for (int m = 0; m < 4; ++m)
#pragma unroll
            for (int n = 0; n < 2; ++n)
                acc[m][n] = __builtin_amdgcn_mfma_f32_16x16x32_bf16(af[m][1], bfr[n][1], acc[m][n], 0, 0, 0);
        __builtin_amdgcn_s_setprio(0);
        if (kt + 2 < NTK) STG_B3(b, kt + 2);

        if (kt < NTK - 2) { asm volatile("s_waitcnt vmcnt(6)" ::: "memory"); }
        else              { asm volatile("s_waitcnt vmcnt(0)" ::: "memory"); }
        __builtin_amdgcn_s_barrier();
    }

    const int colbase = bn_ * 64 + wc * 32;
    const int rowbase = bm_ * 128 + wr * 64;
#pragma unroll
    for (int mt = 0; mt < 4; ++mt)
#pragma unroll
        for (int r = 0; r < 4; ++r) {
            int row = rowbase + mt * 16 + quad * 4 + r;
            float* crow = C + (size_t)row * 2048 + colbase;
#pragma unroll
            for (int nt = 0; nt < 2; ++nt)
                crow[nt * 16 + l16] = acc[mt][nt][r];
        }
}

__device__ __forceinline__ float gelu_exact(float v) {
    return 0.5f * v * (1.0f + erff(v * 0.70710678118654752f));
}

// ---------------------------------------------------------------------------
// MERGED attention dispatch (all inputs produced by the qkv dispatch):
//  Blocks [0,512):     flash local attention, K/V double-buffered with
//                      counted vmcnt (Q in registers); 2 blocks/CU @ 73 KB.
//  Blocks [512,1024):  kvr (3-phase: Pk/Pv resident + Op buffer K->V->Q)
//  Blocks [1024,1536): gate (4 waves x 1 row each)
// ---------------------------------------------------------------------------
#define QTI 64
#define KTI 64
#define PS_LD 72
#define KV_LD 136

// stage K tile (64x128) + V^T tile (128x64) for sbase sb_ into dbuf pointers
#define STG_KV(Kdst, Vdst, sb_) do {                                           \
    _Pragma("unroll")                                                          \
    for (int i_ = 0; i_ < 4; ++i_) {                                           \
        int c_ = i_ * 256 + tid;                                               \
        int row_ = c_ >> 4, pc_ = c_ & 15;                                     \
        int lc_ = pc_ ^ (row_ & 7);                                            \
        async_copy16(qkv_bf + (size_t)((sb_) + row_) * ROW_BF + KB_OFF + h * HD + lc_ * 8, \
                     (Kdst) + c_ * 8);                                         \
    }                                                                          \
    _Pragma("unroll")                                                          \
    for (int i_ = 0; i_ < 4; ++i_) {                                           \
        int c_ = i_ * 256 + tid;                                               \
        int row_ = c_ >> 3, pc_ = c_ & 7;                                      \
        int lc_ = pc_ ^ (row_ & 7);                                            \
        async_copy16(vth + (size_t)row_ * 2048 + (sb_) + lc_ * 8,              \
                     (Vdst) + c_ * 8);                                         \
    }                                                                          \
} while (0)

__global__ __launch_bounds__(256, 2)
void attn_fused(const bf16_t* __restrict__ qkv_bf, const bf16_t* __restrict__ vt,
                bf16_t* __restrict__ cxb,
                const float* __restrict__ pk, const float* __restrict__ pv,
                float* __restrict__ kr, float* __restrict__ vr,
                bf16_t* __restrict__ qr,
                const float* __restrict__ Cpart, const float* __restrict__ w2,
                float* __restrict__ gate) {
    __shared__ __align__(16) unsigned char smem[74752];
    const int bid = blockIdx.x;
    const int tid = threadIdx.x;
    const int wave = tid >> 6, lane = tid & 63;
    const int quad = lane >> 4, l16 = lane & 15;

    if (bid >= 1024) {
        // ---------------- gate: 4 waves, one t per wave ----------------
        const int t = (bid - 1024) * 4 + wave;
        const float* p0 = Cpart + (size_t)t * 512;
        float s = 0.f;
#pragma unroll
        for (int i = lane; i < 512; i += 64) {
            float v = p0[i] + p0[i + 1048576];
            s += gelu_exact(v) * w2[i];
        }
#pragma unroll
        for (int off = 32; off > 0; off >>= 1) s += __shfl_down(s, off);
        if (lane == 0) {
            float sig = 1.f / (1.f + expf(-s));
            gate[t] = (sig > 0.75f) ? 1.f : 0.f;
        }
        return;
    }

    if (bid >= 512) {
        // ---------------- kvr: 3-phase (Pk/Pv resident, Op = K->V->Q) --------
        bf16_t* Pk = (bf16_t*)smem;            // [64][KV_LD]
        bf16_t* Pv = Pk + 64 * KV_LD;
        bf16_t* Op = Pv + 64 * KV_LD;
        const int i0 = bid - 512;
        const int h = i0 >> 5, s0 = (i0 & 31) * 64;

#pragma unroll
        for (int i = 0; i < 8; ++i) {
            int gid = i * 256 + tid;
            int row = gid >> 5, c = (gid & 31) << 2;
            float4 wk = *(const float4*)(pk + (size_t)row * HD + c);
            float4 wv = *(const float4*)(pv + (size_t)row * HD + c);
            bf16x4 qk4, qv4;
            qk4[0] = (bf16_t)wk.x; qk4[1] = (bf16_t)wk.y; qk4[2] = (bf16_t)wk.z; qk4[3] = (bf16_t)wk.w;
            qv4[0] = (bf16_t)wv.x; qv4[1] = (bf16_t)wv.y; qv4[2] = (bf16_t)wv.z; qv4[3] = (bf16_t)wv.w;
            *(bf16x4*)&Pk[row * KV_LD + c] = qk4;
            *(bf16x4*)&Pv[row * KV_LD + c] = qv4;
        }

        f32x4 ak[4], av[4], aq[4];
#pragma unroll
        for (int nt = 0; nt < 4; ++nt) {
            ak[nt] = (f32x4){0.f, 0.f, 0.f, 0.f};
            av[nt] = (f32x4){0.f, 0.f, 0.f, 0.f};
            aq[nt] = (f32x4){0.f, 0.f, 0.f, 0.f};
        }

        // phase 1: K
#pragma unroll
        for (int i = 0; i < 4; ++i) {
            int gid = i * 256 + tid;
            int row = gid >> 4, ch = (gid & 15) << 3;
            *(bf16x8*)&Op[row * KV_LD + ch] =
                *(const bf16x8*)(qkv_bf + (size_t)(s0 + row) * ROW_BF + KB_OFF + h * HD + ch);
        }
        __syncthreads();
#pragma unroll
        for (int ks = 0; ks < 4; ++ks) {
            bf16x8 a = *(const bf16x8*)&Op[(wave * 16 + l16) * KV_LD + ks * 32 + quad * 8];
#pragma unroll
            for (int nt = 0; nt < 4; ++nt) {
                bf16x8 bk = *(const bf16x8*)&Pk[(nt * 16 + l16) * KV_LD + ks * 32 + quad * 8];
                ak[nt] = __builtin_amdgcn_mfma_f32_16x16x32_bf16(a, bk, ak[nt], 0, 0, 0);
            }
        }
        __syncthreads();
        // phase 2: V
#pragma unroll
        for (int i = 0; i < 4; ++i) {
            int gid = i * 256 + tid;
            int row = gid >> 4, ch = (gid & 15) << 3;
            *(bf16x8*)&Op[row * KV_LD + ch] =
                *(const bf16x8*)(qkv_bf + (size_t)(s0 + row) * ROW_BF + VB_OFF + h * HD + ch);
        }
        __syncthreads();
#pragma unroll
        for (int ks = 0; ks < 4; ++ks) {
            bf16x8 a = *(const bf16x8*)&Op[(wave * 16 + l16) * KV_LD + ks * 32 + quad * 8];
#pragma unroll
            for (int nt = 0; nt < 4; ++nt) {
                bf16x8 bv = *(const bf16x8*)&Pv[(nt * 16 + l16) * KV_LD + ks * 32 + quad * 8];
                av[nt] = __builtin_amdgcn_mfma_f32_16x16x32_bf16(a, bv, av[nt], 0, 0, 0);
            }
        }
        __syncthreads();
        // phase 3: Q
#pragma unroll
        for (int i = 0; i < 4; ++i) {
            int gid = i * 256 + tid;
            int row = gid >> 4, ch = (gid & 15) << 3;
            *(bf16x8*)&Op[row * KV_LD + ch] =
                *(const bf16x8*)(qkv_bf + (size_t)(s0 + row) * ROW_BF + h * HD + ch);
        }
        __syncthreads();
#pragma unroll
        for (int ks = 0; ks < 4; ++ks) {
            bf16x8 a = *(const bf16x8*)&Op[(wave * 16 + l16) * KV_LD + ks * 32 + quad * 8];
#pragma unroll
            for (int nt = 0; nt < 4; ++nt) {
                bf16x8 bk = *(const bf16x8*)&Pk[(nt * 16 + l16) * KV_LD + ks * 32 + quad * 8];
                aq[nt] = __builtin_amdgcn_mfma_f32_16x16x32_bf16(a, bk, aq[nt], 0, 0, 0);
            }
        }

#pragma unroll
        for (int nt = 0; nt < 4; ++nt)
#pragma unroll
            for (int r = 0; r < 4; ++r) {
                int s = s0 + wave * 16 + quad * 4 + r;
                size_t idx = ((size_t)h * T_LEN + s) * RANK + nt * 16 + l16;
                kr[idx] = ak[nt][r];
                vr[idx] = av[nt][r];
                qr[idx] = (bf16_t)aq[nt][r];
            }
        return;
    }

    // ---------------- flash local attention (K/V double-buffered) ----------
    bf16_t* Ks  = (bf16_t*)smem;               // [2][64*128]  32 KB
    bf16_t* Vts = Ks + 2 * (KTI * 128);        // [2][128*64]  32 KB
    bf16_t* Psb = Vts + 2 * (128 * KTI);       // [4][16*PS_LD] 9 KB

    const int h = bid >> 5;
    const int t0 = (bid & 31) * QTI;
    const int xsw = l16 & 7;
    const bf16_t* vth = vt + (size_t)h * 128 * 2048;

    const int ktst = (t0 >= 512) ? 0 : (8 - (t0 >> 6));
    const int nval = 9 - ktst;                 // number of valid K-tiles
    const int sb0 = t0 - 512 + ktst * KTI;     // first valid sbase (>= 0)

    // Q fragments in registers (row wave*16+l16, elems ks*32+quad*8)
    bf16x8 qreg[4];
    {
        const bf16_t* qrow = qkv_bf + (size_t)(t0 + wave * 16 + l16) * ROW_BF + h * HD + quad * 8;
#pragma unroll
        for (int ks = 0; ks < 4; ++ks)
            qreg[ks] = *(const bf16x8*)(qrow + ks * 32);
    }
    asm volatile("s_waitcnt vmcnt(0)" ::: "memory");   // Q resident before pipeline

    f32x4 o[8];
#pragma unroll
    for (int d8 = 0; d8 < 8; ++d8) o[d8] = (f32x4){0.f, 0.f, 0.f, 0.f};
    float m_i[4] = {-1e30f, -1e30f, -1e30f, -1e30f};
    float l_i[4] = {0.f, 0.f, 0.f, 0.f};

    // Prologue: stage tiles 0 and 1; wait tile 0, keep tile 1 in flight.
    STG_KV(Ks, Vts, sb0);
    if (nval > 1) {
        STG_KV(Ks + KTI * 128, Vts + 128 * KTI, sb0 + KTI);
        asm volatile("s_waitcnt vmcnt(8)" ::: "memory");
    } else {
        asm volatile("s_waitcnt vmcnt(0)" ::: "memory");
    }
    __builtin_amdgcn_s_barrier();

    for (int j = 0; j < nval; ++j) {
        const int b = j & 1;
        const int sbase = sb0 + j * KTI;
        bf16_t* KsB = Ks + b * (KTI * 128);
        bf16_t* VtB = Vts + b * (128 * KTI);

        f32x4 sacc[4];
#pragma unroll
        for (int nt = 0; nt < 4; ++nt) sacc[nt] = (f32x4){0.f, 0.f, 0.f, 0.f};
#pragma unroll
        for (int ks = 0; ks < 4; ++ks) {
#pragma unroll
            for (int nt = 0; nt < 4; ++nt) {
                bf16x8 bb = *(const bf16x8*)&KsB[(nt * 16 + l16) * 128 + (((ks * 4 + quad) ^ xsw)) * 8];
                sacc[nt] = __builtin_amdgcn_mfma_f32_16x16x32_bf16(qreg[ks], bb, sacc[nt], 0, 0, 0);
            }
        }

#pragma unroll
        for (int nt = 0; nt < 4; ++nt)
#pragma unroll
            for (int r = 0; r < 4; ++r) sacc[nt][r] *= SCALE;

        if ((j == 0 && ktst == 0) || (j == nval - 1)) {   // window edge / diagonal
#pragma unroll
            for (int nt = 0; nt < 4; ++nt) {
                int s_g = sbase + nt * 16 + l16;
#pragma unroll
                for (int r = 0; r < 4; ++r) {
                    int t_g = t0 + wave * 16 + quad * 4 + r;
                    bool valid = (s_g <= t_g) && (s_g + W_LOCAL > t_g);
                    if (!valid) sacc[nt][r] = -1e30f;
                }
            }
        }

#pragma unroll
        for (int r = 0; r < 4; ++r) {
            float mx = fmaxf(fmaxf(sacc[0][r], sacc[1][r]), fmaxf(sacc[2][r], sacc[3][r]));
            mx = fmaxf(mx, __shfl_xor(mx, 1));
            mx = fmaxf(mx, __shfl_xor(mx, 2));
            mx = fmaxf(mx, __shfl_xor(mx, 4));
            mx = fmaxf(mx, __shfl_xor(mx, 8));
            float mnew = fmaxf(m_i[r], mx);
            float alpha = __expf(m_i[r] - mnew);
            m_i[r] = mnew;
            float rs = 0.f;
#pragma unroll
            for (int nt = 0; nt < 4; ++nt) {
                float p = __expf(sacc[nt][r] - mnew);
                sacc[nt][r] = p;
                rs += p;
            }
            rs += __shfl_xor(rs, 1);
            rs += __shfl_xor(rs, 2);
            rs += __shfl_xor(rs, 4);
            rs += __shfl_xor(rs, 8);
            l_i[r] = l_i[r] * alpha + rs;
#pragma unroll
            for (int d8 = 0; d8 < 8; ++d8) o[d8][r] *= alpha;
        }

#pragma unroll
        for (int r = 0; r < 4; ++r)
#pragma unroll
            for (int nt = 0; nt < 4; ++nt)
                Psb[wave * 16 * PS_LD + (quad * 4 + r) * PS_LD + nt * 16 + l16] = (bf16_t)sacc[nt][r];

#pragma unroll
        for (int ks2 = 0; ks2 < 2; ++ks2) {
            bf16x8 a = *(const bf16x8*)&Psb[wave * 16 * PS_LD + l16 * PS_LD + ks2 * 32 + quad * 8];
#pragma unroll
            for (int d8 = 0; d8 < 8; ++d8) {
                int rw = d8 * 16 + l16;
                bf16x8 bb = *(const bf16x8*)&VtB[rw * 64 + (((ks2 * 4 + quad) ^ xsw)) * 8];
                o[d8] = __builtin_amdgcn_mfma_f32_16x16x32_bf16(a, bb, o[d8], 0, 0, 0);
            }
        }

        // ---- pipeline turn: refill buf b with tile j+2 ----
        asm volatile("s_waitcnt lgkmcnt(0)" ::: "memory");
        __builtin_amdgcn_s_barrier();          // all waves done reading buf b
        if (j + 2 < nval) {
            STG_KV(KsB, VtB, sbase + 2 * KTI);
            asm volatile("s_waitcnt vmcnt(8)" ::: "memory");  // tile j+1 landed
        } else {
            asm volatile("s_waitcnt vmcnt(0)" ::: "memory");  // drain tail
        }
        __builtin_amdgcn_s_barrier();
    }

#pragma unroll
    for (int r = 0; r < 4; ++r) {
        float inv = 1.0f / l_i[r];
        size_t rowoff = (size_t)(t0 + wave * 16 + quad * 4 + r) * 2048 + h * HD;
#pragma unroll
        for (int d8 = 0; d8 < 8; ++d8)
            cxb[rowoff + d8 * 16 + l16] = (bf16_t)(o[d8][r] * inv);
    }
}

// ---------------------------------------------------------------------------
// Gated global low-rank branch (early-exit when gate==0); bf16 RMW into cxb
// ---------------------------------------------------------------------------
__device__ __forceinline__ float block_reduce_max512(float v, float* red, int tid) {
    red[tid] = v; __syncthreads();
    for (int s = 256; s > 0; s >>= 1) {
        if (tid < s) red[tid] = fmaxf(red[tid], red[tid + s]);
        __syncthreads();
    }
    float r = red[0]; __syncthreads();
    return r;
}
__device__ __forceinline__ float block_reduce_sum512(float v, float* red, int tid) {
    red[tid] = v; __syncthreads();
    for (int s = 256; s > 0; s >>= 1) {
        if (tid < s) red[tid] = red[tid] + red[tid + s];
        __syncthreads();
    }
    float r = red[0]; __syncthreads();
    return r;
}

__global__ __launch_bounds__(512)
void global_attn_kernel(bf16_t* __restrict__ cxb, const float* __restrict__ kr,
                        const float* __restrict__ vr, const bf16_t* __restrict__ qr,
                        const float* __restrict__ uo, const float* __restrict__ gate) {
    const int t = blockIdx.x, h = blockIdx.y;
    if (gate[t] <= 0.5f) return;

    __shared__ float qrs[64];
    __shared__ float red[512];
    __shared__ float cgr[64];
    __shared__ float sg[2048];
    const int tid = threadIdx.x;

    if (tid < 64) qrs[tid] = (float)qr[((size_t)h * T_LEN + t) * RANK + tid];
    __syncthreads();

    const float* krh = kr + (size_t)h * T_LEN * RANK;
    const float* vrh = vr + (size_t)h * T_LEN * RANK;
    float lmax = -INFINITY;
    for (int s = tid; s < T_LEN; s += 512) {
        const float* krr = krh + (size_t)s * RANK;
        float acc = 0.f;
#pragma unroll
        for (int r = 0; r < RANK; r += 4) {
            float4 k4 = *(const float4*)(krr + r);
            acc += qrs[r] * k4.x + qrs[r + 1] * k4.y + qrs[r + 2] * k4.z + qrs[r + 3] * k4.w;
        }
        float sc = acc * SCALE_G;
        sg[s] = sc;
        lmax = fmaxf(lmax, sc);
    }
    float gmx = block_reduce_max512(lmax, red, tid);
    float lsum = 0.f;
    for (int s = tid; s < T_LEN; s += 512) {
        float pp = expf(sg[s] - gmx);
        sg[s] = pp;
        lsum += pp;
    }
    float gsum = block_reduce_sum512(lsum, red, tid);

    {
        const int r = tid & 63, part = tid >> 6;
        float pacc = 0.f;
        for (int s = part; s < T_LEN; s += 8) pacc += sg[s] * vrh[(size_t)s * RANK + r];
        red[tid] = pacc;
        __syncthreads();
        if (tid < 64) {
            float c = 0.f;
#pragma unroll
            for (int pp = 0; pp < 8; ++pp) c += red[pp * 64 + tid];
            cgr[tid] = c / gsum;
        }
        __syncthreads();
    }

    if (tid < 128) {
        float cg = 0.f;
#pragma unroll
        for (int r = 0; r < RANK; ++r) cg += cgr[r] * uo[tid * RANK + r];
        size_t off = (size_t)t * 2048 + h * HD + tid;
        cxb[off] = (bf16_t)((float)cxb[off] + cg);
    }
}

// ---------------------------------------------------------------------------
extern "C" void kernel_launch(void* const* d_in, const int* in_sizes, int n_in,
                              void* d_out, int out_size, void* d_ws, size_t ws_size,
                              hipStream_t stream) {
    const float* x     = (const float*)d_in[0];
    const float* w_qkv = (const float*)d_in[1];
    const float* w_o   = (const float*)d_in[2];
    const float* pk    = (const float*)d_in[3];
    const float* pv    = (const float*)d_in[4];
    const float* uo    = (const float*)d_in[5];
    const float* w1    = (const float*)d_in[6];
    const float* w2    = (const float*)d_in[7];
    float* out = (float*)d_out;

    // Workspace layout (floats), lifetime-aliased (~88 MB):
    float* ws = (float*)d_ws;
    float* qkv   = ws;                        // 12,582,912 f: bf16 overlay rows
                                              //  q bf16 | K bf16 | wo bf16 | V bf16
    float* hinfo = qkv + (size_t)12582912;    // 1,048,576 f: rope tab, later qr bf16
    float* gatep = hinfo + (size_t)1048576;   // 2048 f
    bf16_t* xb   = (bf16_t*)(gatep + 2048);   // x_hi bf16 (later ctx bf16)
    float* wqbf  = gatep + 2048 + 2097152;    // 6,291,456 f region:
    bf16_t* wqb  = (bf16_t*)wqbf;             //   w_qkv bf16 (entire region)
    float* krp   = wqbf;                      //   later: kr
    float* vrp   = wqbf + (size_t)2097152;    //   later: vr
    float* tabp  = hinfo;                     // rope tables (dead before qr)
    bf16_t* qrp  = (bf16_t*)hinfo;            // qr bf16 (written by attn_fused)
    bf16_t* cxb  = xb;                        // ctx bf16
    bf16_t* qkvb = (bf16_t*)qkv;              // bf16 overlay view of qkv rows
    bf16_t* wob  = qkvb + WO_OFF;             // w_o bf16, row stride ROW_BF
    // d_out doubles as scratch until gemm_ctx_wo overwrites it:
    bf16_t* vtp  = (bf16_t*)d_out;            // V^T [16][128][2048] bf16 (8.39 MB)
    float* ipart = (float*)(vtp + (size_t)16 * 128 * 2048);  // 2x2048x512 f (8.39 MB)

    // 1) merged prep: x->bf16, w_qkv->bf16, rope tables
    prep_kernel<<<8704, 256, 0, stream>>>(x, xb, w_qkv, wqb, tabp);
    // 2) MERGED: info MLP + qkv GEMM v4 (fused RoPE, V overlay + V^T) + w_o->bf16
    gemm_qkv_rope<<<2944, 256, 0, stream>>>(xb, wqb, qkvb, vtp, tabp, w_o, x, w1, ipart);
    // 3) MERGED: local attention (pipelined K/V) + kvr + gate
    attn_fused<<<1536, 256, 0, stream>>>(qkvb, vtp, cxb, pk, pv, krp, vrp, qrp,
                                         ipart, w2, gatep);
    // 4) gated global branch (bf16 RMW into cxb)
    global_attn_kernel<<<dim3(T_LEN, NH), 512, 0, stream>>>(cxb, krp, vrp, qrp, uo, gatep);
    // 5) out = ctx @ w_o^T  (v4 pipelined, 128x64 tiles, 2 blocks/CU)
    gemm_ctx_wo<<<512, 256, 0, stream>>>(cxb, wob, out);
}

// Round 11
// 282.528 us; speedup vs baseline: 1.0036x; 1.0036x over previous
//
#include <hip/hip_runtime.h>
#include <hip/hip_bf16.h>
#include <math.h>

// Problem constants
#define T_LEN 2048
#define C_DIM 2048
#define NH 16
#define HD 128
#define RANK 64
#define W_LOCAL 512
#define QKV_LD 6144
#define ROW_BF 12288          // qkv row stride in bf16 elems
#define KB_OFF 4096           // bf16-elem offset of packed K overlay within row
#define VB_OFF 8192           // bf16-elem offset of packed V overlay within row
#define WO_OFF 6144           // bf16-elem offset of packed w_o row within qkv row
#define SCALE 0.08838834764831845f    // 1/sqrt(128)
#define SCALE_G 0.17677669529663687f  // scale * 128/64
#define LOG1E4_OVER_64 0.14391156831212787f

typedef __bf16 bf16_t;
typedef __bf16 bf16x8 __attribute__((ext_vector_type(8)));
typedef __bf16 bf16x4 __attribute__((ext_vector_type(4)));
typedef float f32x4 __attribute__((ext_vector_type(4)));

// ---------------------------------------------------------------------------
// async 16B global -> LDS (gfx950). LDS dst must be wave-uniform base+lane*16.
// ---------------------------------------------------------------------------
__device__ __forceinline__ void async_copy16(const bf16_t* g, bf16_t* l) {
    __builtin_amdgcn_global_load_lds(
        (const __attribute__((address_space(1))) unsigned int*)g,
        (__attribute__((address_space(3))) unsigned int*)l, 16, 0, 0);
}

// ---------------------------------------------------------------------------
// Merged prep kernel (block-range dispatch):
//  [0,2048):    x -> xb bf16 (hi only; info MLP re-derives lo from fp32 x)
//  [2048,8192): w_qkv -> wqb bf16
//  [8192,8704): rope tables
// ---------------------------------------------------------------------------
__global__ __launch_bounds__(256)
void prep_kernel(const float* __restrict__ x, bf16_t* __restrict__ xb,
                 const float* __restrict__ w_qkv, bf16_t* __restrict__ wqb,
                 float* __restrict__ tab) {
    const int bid = blockIdx.x;
    const int tid = threadIdx.x;
    if (bid < 2048) {
        int idx = bid * 256 + tid;                   // 8 elems each
        const float* p = x + (size_t)idx * 8;
        float4 v0 = *(const float4*)p;
        float4 v1 = *(const float4*)(p + 4);
        bf16x8 o;
        o[0] = (bf16_t)v0.x; o[1] = (bf16_t)v0.y; o[2] = (bf16_t)v0.z; o[3] = (bf16_t)v0.w;
        o[4] = (bf16_t)v1.x; o[5] = (bf16_t)v1.y; o[6] = (bf16_t)v1.z; o[7] = (bf16_t)v1.w;
        *(bf16x8*)(xb + (size_t)idx * 8) = o;
    } else if (bid < 8192) {
        // w_qkv fp32 -> bf16 (6144x2048)
        int idx = (bid - 2048) * 256 + tid;          // 8 elems each
        const float* p = w_qkv + (size_t)idx * 8;
        float4 v0 = *(const float4*)p;
        float4 v1 = *(const float4*)(p + 4);
        bf16x8 o;
        o[0] = (bf16_t)v0.x; o[1] = (bf16_t)v0.y; o[2] = (bf16_t)v0.z; o[3] = (bf16_t)v0.w;
        o[4] = (bf16_t)v1.x; o[5] = (bf16_t)v1.y; o[6] = (bf16_t)v1.z; o[7] = (bf16_t)v1.w;
        *(bf16x8*)(wqb + (size_t)idx * 8) = o;
    } else {
        // rope tables
        int idx = (bid - 8192) * 256 + tid;          // 2048*64
        int t = idx >> 6, j = idx & 63;
        float inv = expf(-(float)j * LOG1E4_OVER_64);
        float s, c;
        sincosf((float)t * inv, &s, &c);
        tab[t * 128 + j] = c;
        tab[t * 128 + 64 + j] = s;
    }
}

// ---------------------------------------------------------------------------
// MERGED dispatch: info-MLP GEMM + qkv GEMM v4 + piggy-backed w_o conversion.
//  Blocks [0,128):    info MLP split-bf16 GEMM (split-K=2), reg-staged from
//                     fp32 x/w1, partials->ipart (second half of d_out).
//  Blocks [128,896):  qkv GEMM 128x128/BK=64/2 blocks/CU, counted vmcnt,
//                     both-sides XOR swizzle, fused RoPE epilogue, V overlay
//                     + V^T (vt, first half of d_out).
//                     bn-FASTEST within XCD: B-stripe stays L2-resident.
//  Blocks [896,2944): w_o row -> bf16 WO_OFF overlay.
// ---------------------------------------------------------------------------
#define NTK 32      // 2048 / 64
#define ILD 40      // info LDS leading dim (padded: 128x40 bf16 per buffer)

#define STG_A(bb, ktile) do {                                                  \
    _Pragma("unroll")                                                          \
    for (int c_ = 0; c_ < 4; ++c_)                                             \
        async_copy16(gA + (size_t)(c_ * 32) * 2048 + (ktile) * 64,             \
                     &lds[bb][0][(c_ * 32 + rS) * 64 + dS]);                   \
} while (0)

#define STG_B(bb, ktile) do {                                                  \
    _Pragma("unroll")                                                          \
    for (int c_ = 0; c_ < 4; ++c_)                                             \
        async_copy16(gB + (size_t)(c_ * 32) * 2048 + (ktile) * 64,             \
                     &lds[bb][1][(c_ * 32 + rS) * 64 + dS]);                   \
} while (0)

#define RD_A(bb, m, k) (*(const bf16x8*)&lds[bb][0][(wr * 64 + (m) * 16 + l16) * 64 + (((k) * 4 + quad) ^ xsw) * 8])
#define RD_B(bb, n, k) (*(const bf16x8*)&lds[bb][1][(wc * 64 + (n) * 16 + l16) * 64 + (((k) * 4 + quad) ^ xsw) * 8])

__global__ __launch_bounds__(256, 2)
void gemm_qkv_rope(const bf16_t* __restrict__ A, const bf16_t* __restrict__ B,
                   bf16_t* __restrict__ qkv_bf, bf16_t* __restrict__ vt,
                   const float* __restrict__ tab, const float* __restrict__ w_o,
                   const float* __restrict__ x, const float* __restrict__ w1,
                   float* __restrict__ ipart) {
    __shared__ __align__(16) unsigned char smem[65536];
    const int bid = blockIdx.x;
    const int tid = threadIdx.x;

    if (bid < 128) {
        // ---------------- info MLP block (split-bf16, 3x MFMA) ----------------
        bf16_t* Ah = (bf16_t*)smem;            // [128][ILD]
        bf16_t* Al = Ah + 128 * ILD;
        bf16_t* Bh = Al + 128 * ILD;
        bf16_t* Bl = Bh + 128 * ILD;
        const int bn = bid & 3, bm = (bid >> 2) & 15, ks = bid >> 6;
        const int wave = tid >> 6, lane = tid & 63;
        const int quad = lane >> 4, l16 = lane & 15;
        const int wm = (wave >> 1) * 64, wn = (wave & 1) * 64;
        const int lrow = lane >> 2;
        const int lkb = (lane & 3) * 8;
        const int kbeg = ks * 1024;

        f32x4 acc[4][4];
#pragma unroll
        for (int i = 0; i < 4; ++i)
#pragma unroll
            for (int j = 0; j < 4; ++j) acc[i][j] = (f32x4){0.f, 0.f, 0.f, 0.f};

        const float* gx = x + (size_t)(bm * 128 + wave * 16 + lrow) * 2048 + kbeg + lkb;
        const float* gw = w1 + (size_t)(bn * 128 + wave * 16 + lrow) * 2048 + kbeg + lkb;
        const int wrow = (wave * 16 + lrow) * ILD + lkb;

        for (int k0 = 0; k0 < 1024; k0 += 32) {
            __syncthreads();
#pragma unroll
            for (int hr = 0; hr < 2; ++hr) {
                const float* px = gx + (size_t)hr * 64 * 2048 + k0;
                float4 a0 = *(const float4*)px, a1 = *(const float4*)(px + 4);
                float av[8] = {a0.x, a0.y, a0.z, a0.w, a1.x, a1.y, a1.z, a1.w};
                bf16x8 h, l;
#pragma unroll
                for (int i = 0; i < 8; ++i) {
                    bf16_t hb = (bf16_t)av[i];
                    h[i] = hb; l[i] = (bf16_t)(av[i] - (float)hb);
                }
                *(bf16x8*)&Ah[wrow + hr * 64 * ILD] = h;
                *(bf16x8*)&Al[wrow + hr * 64 * ILD] = l;

                const float* pw = gw + (size_t)hr * 64 * 2048 + k0;
                float4 b0 = *(const float4*)pw, b1 = *(const float4*)(pw + 4);
                float bv[8] = {b0.x, b0.y, b0.z, b0.w, b1.x, b1.y, b1.z, b1.w};
                bf16x8 hb2, lb2;
#pragma unroll
                for (int i = 0; i < 8; ++i) {
                    bf16_t hh = (bf16_t)bv[i];
                    hb2[i] = hh; lb2[i] = (bf16_t)(bv[i] - (float)hh);
                }
                *(bf16x8*)&Bh[wrow + hr * 64 * ILD] = hb2;
                *(bf16x8*)&Bl[wrow + hr * 64 * ILD] = lb2;
            }
            __syncthreads();

            bf16x8 ah[4], al[4], bh[4], bl[4];
#pragma unroll
            for (int mt = 0; mt < 4; ++mt) {
                ah[mt] = *(const bf16x8*)&Ah[(wm + mt * 16 + l16) * ILD + quad * 8];
                al[mt] = *(const bf16x8*)&Al[(wm + mt * 16 + l16) * ILD + quad * 8];
            }
#pragma unroll
            for (int nt = 0; nt < 4; ++nt) {
                bh[nt] = *(const bf16x8*)&Bh[(wn + nt * 16 + l16) * ILD + quad * 8];
                bl[nt] = *(const bf16x8*)&Bl[(wn + nt * 16 + l16) * ILD + quad * 8];
            }
#pragma unroll
            for (int mt = 0; mt < 4; ++mt)
#pragma unroll
                for (int nt = 0; nt < 4; ++nt) {
                    acc[mt][nt] = __builtin_amdgcn_mfma_f32_16x16x32_bf16(ah[mt], bh[nt], acc[mt][nt], 0, 0, 0);
                    acc[mt][nt] = __builtin_amdgcn_mfma_f32_16x16x32_bf16(ah[mt], bl[nt], acc[mt][nt], 0, 0, 0);
                    acc[mt][nt] = __builtin_amdgcn_mfma_f32_16x16x32_bf16(al[mt], bh[nt], acc[mt][nt], 0, 0, 0);
                }
        }

        float* cp = ipart + (size_t)ks * 2048 * 512;
#pragma unroll
        for (int mt = 0; mt < 4; ++mt)
#pragma unroll
            for (int r = 0; r < 4; ++r) {
                int row = bm * 128 + wm + mt * 16 + quad * 4 + r;
                float* crow = cp + (size_t)row * 512 + bn * 128 + wn;
#pragma unroll
                for (int nt = 0; nt < 4; ++nt)
                    crow[nt * 16 + l16] = acc[mt][nt][r];
            }
        return;
    }

    if (bid >= 896) {
        // ---------------- w_o conversion: one row per block ----------------
        int row = bid - 896;
        int c = tid * 8;
        const float* p = w_o + (size_t)row * 2048 + c;
        float4 v0 = *(const float4*)p;
        float4 v1 = *(const float4*)(p + 4);
        bf16x8 o;
        o[0] = (bf16_t)v0.x; o[1] = (bf16_t)v0.y; o[2] = (bf16_t)v0.z; o[3] = (bf16_t)v0.w;
        o[4] = (bf16_t)v1.x; o[5] = (bf16_t)v1.y; o[6] = (bf16_t)v1.z; o[7] = (bf16_t)v1.w;
        *(bf16x8*)(qkv_bf + (size_t)row * ROW_BF + WO_OFF + c) = o;
        return;
    }

    // ---------------- qkv GEMM v4 block ----------------
    typedef bf16_t ldsbuf_t[2][128 * 64];
    ldsbuf_t* lds = (ldsbuf_t*)smem;           // [2][2][8192], 64 KiB

    const int gid = bid - 128;                 // 0..767
    const int xcd = gid & 7, idx = gid >> 3;   // 96 blocks per XCD
    const int bn_ = xcd * 6 + (idx % 6);       // bn FASTEST: B-stripe L2-resident
    const int bm_ = idx / 6;                   // 0..15
    const int wave = tid >> 6, lane = tid & 63;
    const int quad = lane >> 4, l16 = lane & 15;
    const int wr = wave >> 1, wc = wave & 1;   // 2x2 wave grid, wave tile 64x64
    const int xsw = l16 & 7;

    // staging geometry: thread covers (row rS + 32*c, phys chunk tid&7);
    // global source chunk pre-swizzled: phys chunk p holds logical p^(row&7)
    const int rS = tid >> 3;                   // 0..31
    const int cS = ((tid & 7) ^ (rS & 7)) * 8; // global col (bf16)
    const int dS = (tid & 7) * 8;              // linear LDS chunk
    const bf16_t* gA = A + (size_t)(bm_ * 128 + rS) * 2048 + cS;
    const bf16_t* gB = B + (size_t)(bn_ * 128 + rS) * 2048 + cS;

    f32x4 acc[4][4];
#pragma unroll
    for (int i = 0; i < 4; ++i)
#pragma unroll
        for (int j = 0; j < 4; ++j) acc[i][j] = (f32x4){0.f, 0.f, 0.f, 0.f};

    // Prologue: stage tiles 0 and 1; wait for tile 0, leave tile 1 in flight.
    STG_A(0, 0); STG_B(0, 0);
    STG_A(1, 1); STG_B(1, 1);
    asm volatile("s_waitcnt vmcnt(8)" ::: "memory");
    __builtin_amdgcn_s_barrier();

    for (int kt = 0; kt < NTK; ++kt) {
        const int b = kt & 1;
        bf16x8 af[4][2], bfr[4][2];
#pragma unroll
        for (int m = 0; m < 4; ++m) { af[m][0] = RD_A(b, m, 0); af[m][1] = RD_A(b, m, 1); }
#pragma unroll
        for (int n = 0; n < 4; ++n) { bfr[n][0] = RD_B(b, n, 0); bfr[n][1] = RD_B(b, n, 1); }
        asm volatile("s_waitcnt lgkmcnt(0)" ::: "memory");
        __builtin_amdgcn_s_barrier();          // all waves done reading buf b

        __builtin_amdgcn_s_setprio(1);
#pragma unroll
        for (int m = 0; m < 4; ++m)
#pragma unroll
            for (int n = 0; n < 4; ++n)
                acc[m][n] = __builtin_amdgcn_mfma_f32_16x16x32_bf16(af[m][0], bfr[n][0], acc[m][n], 0, 0, 0);
        __builtin_amdgcn_s_setprio(0);
        if (kt + 2 < NTK) STG_A(b, kt + 2);    // buf b safe to overwrite now

        __builtin_amdgcn_s_setprio(1);
#pragma unroll
        for (int m = 0; m < 4; ++m)
#pragma unroll
            for (int n = 0; n < 4; ++n)
                acc[m][n] = __builtin_amdgcn_mfma_f32_16x16x32_bf16(af[m][1], bfr[n][1], acc[m][n], 0, 0, 0);
        __builtin_amdgcn_s_setprio(0);
        if (kt + 2 < NTK) STG_B(b, kt + 2);

        if (kt < NTK - 2) { asm volatile("s_waitcnt vmcnt(8)" ::: "memory"); }
        else              { asm volatile("s_waitcnt vmcnt(0)" ::: "memory"); }
        __builtin_amdgcn_s_barrier();
    }

    // ---- epilogue ----
    const int colbase = bn_ * 128 + wc * 64;
    const int region = (bn_ * 128) >> 11;      // 0=q, 1=k, 2=v (block-uniform)
    const int rowbase = bm_ * 128 + wr * 64;
    const bool odd = (l16 & 1);

    if (region == 2) {
        // (a) row-major V overlay (for kvr)
#pragma unroll
        for (int mt = 0; mt < 4; ++mt)
#pragma unroll
            for (int r = 0; r < 4; ++r) {
                int t = rowbase + mt * 16 + quad * 4 + r;
                bf16_t* brow = qkv_bf + (size_t)t * ROW_BF + VB_OFF + (colbase - 4096);
#pragma unroll
                for (int nt = 0; nt < 4; ++nt)
                    brow[nt * 16 + l16] = (bf16_t)acc[mt][nt][r];
            }
        // (b) transposed vt[h][d][t] via LDS transpose (tile = exactly one head)
        bf16_t* Tl = (bf16_t*)smem;            // [128][136] bf16, 34.8 KB
#pragma unroll
        for (int mt = 0; mt < 4; ++mt)
#pragma unroll
            for (int r = 0; r < 4; ++r) {
                int rloc = wr * 64 + mt * 16 + quad * 4 + r;
#pragma unroll
                for (int nt = 0; nt < 4; ++nt) {
                    int cloc = wc * 64 + nt * 16 + l16;
                    Tl[cloc * 136 + rloc] = (bf16_t)acc[mt][nt][r];
                }
            }
        __syncthreads();
        const int hh = bn_ - 32;               // head index
        const int d = tid >> 1, th = (tid & 1) * 64;
        bf16_t* dst = vt + ((size_t)(hh * 128 + d)) * 2048 + bm_ * 128 + th;
        const bf16_t* srcT = Tl + d * 136 + th;
#pragma unroll
        for (int j = 0; j < 8; ++j)
            *(bf16x8*)(dst + j * 8) = *(const bf16x8*)(srcT + j * 8);
    } else {
        // RoPE for q/k; store bf16 overlay (q @0, k @KB_OFF)
#pragma unroll
        for (int mt = 0; mt < 4; ++mt)
#pragma unroll
            for (int r = 0; r < 4; ++r) {
                int t = rowbase + mt * 16 + quad * 4 + r;
                const float* trow = tab + t * 128;
#pragma unroll
                for (int nt = 0; nt < 4; ++nt) {
                    float v = acc[mt][nt][r];
                    float vp = __shfl_xor(v, 1);    // pair column value
                    int col = colbase + nt * 16 + l16;
                    int j = col & 63;
                    float c = trow[j], s = trow[64 + j];
                    float y = odd ? (v * c + vp * s) : (v * c - vp * s);
                    qkv_bf[(size_t)t * ROW_BF + (region == 0 ? col : col + 2048)] = (bf16_t)y;
                }
            }
    }
}

// ---------------------------------------------------------------------------
// Final GEMM: out = ctx @ w_o^T, v4 pipeline, 128x64 tile -> 512 blocks
// (2 blocks/CU). bn-fastest within XCD (B-stripe 1 MB L2-resident).
// Counted vmcnt(6); both-sides swizzle.
// ---------------------------------------------------------------------------
#define STG_A3(bb, ktile) do {                                                 \
    _Pragma("unroll")                                                          \
    for (int c_ = 0; c_ < 4; ++c_)                                             \
        async_copy16(gA + (size_t)(c_ * 32) * 2048 + (ktile) * 64,             \
                     &ldsA[bb][(c_ * 32 + rS) * 64 + dS]);                     \
} while (0)

#define STG_B3(bb, ktile) do {                                                 \
    _Pragma("unroll")                                                          \
    for (int c_ = 0; c_ < 2; ++c_)                                             \
        async_copy16(gB + (size_t)(c_ * 32) * ROW_BF + (ktile) * 64,           \
                     &ldsB[bb][(c_ * 32 + rS) * 64 + dS]);                     \
} while (0)

#define RD_A3(bb, m, k) (*(const bf16x8*)&ldsA[bb][(wr * 64 + (m) * 16 + l16) * 64 + (((k) * 4 + quad) ^ xsw) * 8])
#define RD_B3(bb, n, k) (*(const bf16x8*)&ldsB[bb][(wc * 32 + (n) * 16 + l16) * 64 + (((k) * 4 + quad) ^ xsw) * 8])

__global__ __launch_bounds__(256, 2)
void gemm_ctx_wo(const bf16_t* __restrict__ A, const bf16_t* __restrict__ Bov,
                 float* __restrict__ C) {
    __shared__ __align__(16) bf16_t ldsA[2][128 * 64];   // 32 KiB
    __shared__ __align__(16) bf16_t ldsB[2][64 * 64];    // 16 KiB

    const int bid = blockIdx.x;                // 0..511
    const int xcd = bid & 7, idx = bid >> 3;   // 64 blocks per XCD
    const int bn_ = xcd * 4 + (idx & 3);       // bn FASTEST: B-stripe L2-resident
    const int bm_ = idx >> 2;                  // 0..15
    const int tid = threadIdx.x;
    const int wave = tid >> 6, lane = tid & 63;
    const int quad = lane >> 4, l16 = lane & 15;
    const int wr = wave >> 1, wc = wave & 1;   // wave tile 64x32
    const int xsw = l16 & 7;

    const int rS = tid >> 3;
    const int cS = ((tid & 7) ^ (rS & 7)) * 8;
    const int dS = (tid & 7) * 8;
    const bf16_t* gA = A + (size_t)(bm_ * 128 + rS) * 2048 + cS;
    const bf16_t* gB = Bov + (size_t)(bn_ * 64 + rS) * ROW_BF + cS;

    f32x4 acc[4][2];
#pragma unroll
    for (int i = 0; i < 4; ++i)
#pragma unroll
        for (int j = 0; j < 2; ++j) acc[i][j] = (f32x4){0.f, 0.f, 0.f, 0.f};

    STG_A3(0, 0); STG_B3(0, 0);
    STG_A3(1, 1); STG_B3(1, 1);
    asm volatile("s_waitcnt vmcnt(6)" ::: "memory");
    __builtin_amdgcn_s_barrier();

    for (int kt = 0; kt < NTK; ++kt) {
        const int b = kt & 1;
        bf16x8 af[4][2], bfr[2][2];
#pragma unroll
        for (int m = 0; m < 4; ++m) { af[m][0] = RD_A3(b, m, 0); af[m][1] = RD_A3(b, m, 1); }
#pragma unroll
        for (int n = 0; n < 2; ++n) { bfr[n][0] = RD_B3(b, n, 0); bfr[n][1] = RD_B3(b, n, 1); }
        asm volatile("s_waitcnt lgkmcnt(0)" ::: "memory");
        __builtin_amdgcn_s_barrier();

        __builtin_amdgcn_s_setprio(1);
#pragma unroll
        for (int m = 0; m < 4; ++m)
#pragma unroll
            for (int n = 0; n < 2; ++n)
                acc[m][n] = __builtin_amdgcn_mfma_f32_16x16x32_bf16(af[m][0], bfr[n][0], acc[m][n], 0, 0, 0);
        __builtin_amdgcn_s_setprio(0);
        if (kt + 2 < NTK) STG_A3(b, kt + 2);

        __builtin_amdgcn_s_setprio(1);
#pragma unroll
        for (int m = 0; m < 4; ++m)
#pragma unroll
            for (int n = 0; n < 2; ++n)
                acc[m][n] = __builtin_amdgcn_mfma_f32_16x16x32_bf16(af[m][1], bfr[n][1], acc[m][n], 0, 0, 0);
        __builtin_amdgcn_s_setprio(0);
        if (kt + 2 < NTK) STG_B3(b, kt + 2);

        if (kt < NTK - 2) { asm volatile("s_waitcnt vmcnt(6)" ::: "memory"); }
        else              { asm volatile("s_waitcnt vmcnt(0)" ::: "memory"); }
        __builtin_amdgcn_s_barrier();
    }

    const int colbase = bn_ * 64 + wc * 32;
    const int rowbase = bm_ * 128 + wr * 64;
#pragma unroll
    for (int mt = 0; mt < 4; ++mt)
#pragma unroll
        for (int r = 0; r < 4; ++r) {
            int row = rowbase + mt * 16 + quad * 4 + r;
            float* crow = C + (size_t)row * 2048 + colbase;
#pragma unroll
            for (int nt = 0; nt < 2; ++nt)
                crow[nt * 16 + l16] = acc[mt][nt][r];
        }
}

__device__ __forceinline__ float gelu_exact(float v) {
    return 0.5f * v * (1.0f + erff(v * 0.70710678118654752f));
}

// ---------------------------------------------------------------------------
// MERGED attention dispatch (all inputs produced by the qkv dispatch):
//  Blocks [0,512):     flash local attention (h = bid>>5, t0 = (bid&31)*64)
//  Blocks [512,1024):  kvr (3-phase: Pk/Pv resident + Op buffer K->V->Q)
//  Blocks [1024,1536): gate (4 waves x 1 row each)
// LDS union = local's 58368 B -> 2 blocks/CU.
// ---------------------------------------------------------------------------
#define QTI 64
#define KTI 64
#define PS_LD 72
#define KV_LD 136

__global__ __launch_bounds__(256, 2)
void attn_fused(const bf16_t* __restrict__ qkv_bf, const bf16_t* __restrict__ vt,
                bf16_t* __restrict__ cxb,
                const float* __restrict__ pk, const float* __restrict__ pv,
                float* __restrict__ kr, float* __restrict__ vr,
                bf16_t* __restrict__ qr,
                const float* __restrict__ Cpart, const float* __restrict__ w2,
                float* __restrict__ gate) {
    __shared__ __align__(16) unsigned char smem[58368];
    const int bid = blockIdx.x;
    const int tid = threadIdx.x;
    const int wave = tid >> 6, lane = tid & 63;
    const int quad = lane >> 4, l16 = lane & 15;

    if (bid >= 1024) {
        // ---------------- gate: 4 waves, one t per wave ----------------
        const int t = (bid - 1024) * 4 + wave;
        const float* p0 = Cpart + (size_t)t * 512;
        float s = 0.f;
#pragma unroll
        for (int i = lane; i < 512; i += 64) {
            float v = p0[i] + p0[i + 1048576];
            s += gelu_exact(v) * w2[i];
        }
#pragma unroll
        for (int off = 32; off > 0; off >>= 1) s += __shfl_down(s, off);
        if (lane == 0) {
            float sig = 1.f / (1.f + expf(-s));
            gate[t] = (sig > 0.75f) ? 1.f : 0.f;
        }
        return;
    }

    if (bid >= 512) {
        // ---------------- kvr: 3-phase (Pk/Pv resident, Op = K->V->Q) --------
        bf16_t* Pk = (bf16_t*)smem;            // [64][KV_LD]
        bf16_t* Pv = Pk + 64 * KV_LD;
        bf16_t* Op = Pv + 64 * KV_LD;
        const int i0 = bid - 512;
        const int h = i0 >> 5, s0 = (i0 & 31) * 64;

#pragma unroll
        for (int i = 0; i < 8; ++i) {
            int gid = i * 256 + tid;
            int row = gid >> 5, c = (gid & 31) << 2;
            float4 wk = *(const float4*)(pk + (size_t)row * HD + c);
            float4 wv = *(const float4*)(pv + (size_t)row * HD + c);
            bf16x4 qk4, qv4;
            qk4[0] = (bf16_t)wk.x; qk4[1] = (bf16_t)wk.y; qk4[2] = (bf16_t)wk.z; qk4[3] = (bf16_t)wk.w;
            qv4[0] = (bf16_t)wv.x; qv4[1] = (bf16_t)wv.y; qv4[2] = (bf16_t)wv.z; qv4[3] = (bf16_t)wv.w;
            *(bf16x4*)&Pk[row * KV_LD + c] = qk4;
            *(bf16x4*)&Pv[row * KV_LD + c] = qv4;
        }

        f32x4 ak[4], av[4], aq[4];
#pragma unroll
        for (int nt = 0; nt < 4; ++nt) {
            ak[nt] = (f32x4){0.f, 0.f, 0.f, 0.f};
            av[nt] = (f32x4){0.f, 0.f, 0.f, 0.f};
            aq[nt] = (f32x4){0.f, 0.f, 0.f, 0.f};
        }

        // phase 1: K
#pragma unroll
        for (int i = 0; i < 4; ++i) {
            int gid = i * 256 + tid;
            int row = gid >> 4, ch = (gid & 15) << 3;
            *(bf16x8*)&Op[row * KV_LD + ch] =
                *(const bf16x8*)(qkv_bf + (size_t)(s0 + row) * ROW_BF + KB_OFF + h * HD + ch);
        }
        __syncthreads();
#pragma unroll
        for (int ks = 0; ks < 4; ++ks) {
            bf16x8 a = *(const bf16x8*)&Op[(wave * 16 + l16) * KV_LD + ks * 32 + quad * 8];
#pragma unroll
            for (int nt = 0; nt < 4; ++nt) {
                bf16x8 bk = *(const bf16x8*)&Pk[(nt * 16 + l16) * KV_LD + ks * 32 + quad * 8];
                ak[nt] = __builtin_amdgcn_mfma_f32_16x16x32_bf16(a, bk, ak[nt], 0, 0, 0);
            }
        }
        __syncthreads();
        // phase 2: V
#pragma unroll
        for (int i = 0; i < 4; ++i) {
            int gid = i * 256 + tid;
            int row = gid >> 4, ch = (gid & 15) << 3;
            *(bf16x8*)&Op[row * KV_LD + ch] =
                *(const bf16x8*)(qkv_bf + (size_t)(s0 + row) * ROW_BF + VB_OFF + h * HD + ch);
        }
        __syncthreads();
#pragma unroll
        for (int ks = 0; ks < 4; ++ks) {
            bf16x8 a = *(const bf16x8*)&Op[(wave * 16 + l16) * KV_LD + ks * 32 + quad * 8];
#pragma unroll
            for (int nt = 0; nt < 4; ++nt) {
                bf16x8 bv = *(const bf16x8*)&Pv[(nt * 16 + l16) * KV_LD + ks * 32 + quad * 8];
                av[nt] = __builtin_amdgcn_mfma_f32_16x16x32_bf16(a, bv, av[nt], 0, 0, 0);
            }
        }
        __syncthreads();
        // phase 3: Q
#pragma unroll
        for (int i = 0; i < 4; ++i) {
            int gid = i * 256 + tid;
            int row = gid >> 4, ch = (gid & 15) << 3;
            *(bf16x8*)&Op[row * KV_LD + ch] =
                *(const bf16x8*)(qkv_bf + (size_t)(s0 + row) * ROW_BF + h * HD + ch);
        }
        __syncthreads();
#pragma unroll
        for (int ks = 0; ks < 4; ++ks) {
            bf16x8 a = *(const bf16x8*)&Op[(wave * 16 + l16) * KV_LD + ks * 32 + quad * 8];
#pragma unroll
            for (int nt = 0; nt < 4; ++nt) {
                bf16x8 bk = *(const bf16x8*)&Pk[(nt * 16 + l16) * KV_LD + ks * 32 + quad * 8];
                aq[nt] = __builtin_amdgcn_mfma_f32_16x16x32_bf16(a, bk, aq[nt], 0, 0, 0);
            }
        }

#pragma unroll
        for (int nt = 0; nt < 4; ++nt)
#pragma unroll
            for (int r = 0; r < 4; ++r) {
                int s = s0 + wave * 16 + quad * 4 + r;
                size_t idx = ((size_t)h * T_LEN + s) * RANK + nt * 16 + l16;
                kr[idx] = ak[nt][r];
                vr[idx] = av[nt][r];
                qr[idx] = (bf16_t)aq[nt][r];
            }
        return;
    }

    // ---------------- flash local attention ----------------
    bf16_t* Qs  = (bf16_t*)smem;               // [QTI*128]
    bf16_t* Ks  = Qs + QTI * 128;
    bf16_t* Vts = Ks + KTI * 128;              // [128*KTI]
    bf16_t* Psb = Vts + 128 * KTI;             // [4][16*PS_LD]

    const int h = bid >> 5;
    const int t0 = (bid & 31) * QTI;
    const int xsw = l16 & 7;

    const bf16_t* vth = vt + (size_t)h * 128 * 2048;

    // stage Q once (async, swizzled)
#pragma unroll
    for (int i = 0; i < 4; ++i) {
        int c = i * 256 + tid;
        int row = c >> 4, pc = c & 15;
        int lc = pc ^ (row & 7);
        async_copy16(qkv_bf + (size_t)(t0 + row) * ROW_BF + h * HD + lc * 8, &Qs[c * 8]);
    }

    f32x4 o[8];
#pragma unroll
    for (int d8 = 0; d8 < 8; ++d8) o[d8] = (f32x4){0.f, 0.f, 0.f, 0.f};
    float m_i[4] = {-1e30f, -1e30f, -1e30f, -1e30f};
    float l_i[4] = {0.f, 0.f, 0.f, 0.f};

    __syncthreads();

    for (int kt = 0; kt < 9; ++kt) {
        const int sbase = t0 - 512 + kt * KTI;
        if (sbase < 0) continue;
        __syncthreads();
        // K tile [64 s][128 d], async swizzled
#pragma unroll
        for (int i = 0; i < 4; ++i) {
            int c = i * 256 + tid;
            int row = c >> 4, pc = c & 15;
            int lc = pc ^ (row & 7);
            async_copy16(qkv_bf + (size_t)(sbase + row) * ROW_BF + KB_OFF + h * HD + lc * 8,
                         &Ks[c * 8]);
        }
        // V^T tile [128 d][64 s], async swizzled
#pragma unroll
        for (int i = 0; i < 4; ++i) {
            int c = i * 256 + tid;
            int row = c >> 3, pc = c & 7;
            int lc = pc ^ (row & 7);
            async_copy16(vth + (size_t)row * 2048 + sbase + lc * 8, &Vts[c * 8]);
        }
        __syncthreads();

        f32x4 sacc[4];
#pragma unroll
        for (int nt = 0; nt < 4; ++nt) sacc[nt] = (f32x4){0.f, 0.f, 0.f, 0.f};
#pragma unroll
        for (int ks = 0; ks < 4; ++ks) {
            bf16x8 a = *(const bf16x8*)&Qs[(wave * 16 + l16) * 128 + (((ks * 4 + quad) ^ xsw)) * 8];
#pragma unroll
            for (int nt = 0; nt < 4; ++nt) {
                bf16x8 b = *(const bf16x8*)&Ks[(nt * 16 + l16) * 128 + (((ks * 4 + quad) ^ xsw)) * 8];
                sacc[nt] = __builtin_amdgcn_mfma_f32_16x16x32_bf16(a, b, sacc[nt], 0, 0, 0);
            }
        }

#pragma unroll
        for (int nt = 0; nt < 4; ++nt)
#pragma unroll
            for (int r = 0; r < 4; ++r) sacc[nt][r] *= SCALE;

        if (kt == 0 || kt == 8) {   // uniform branch; interior tiles need no mask
#pragma unroll
            for (int nt = 0; nt < 4; ++nt) {
                int s_g = sbase + nt * 16 + l16;
#pragma unroll
                for (int r = 0; r < 4; ++r) {
                    int t_g = t0 + wave * 16 + quad * 4 + r;
                    bool valid = (s_g <= t_g) && (s_g + W_LOCAL > t_g);
                    if (!valid) sacc[nt][r] = -1e30f;
                }
            }
        }

#pragma unroll
        for (int r = 0; r < 4; ++r) {
            float mx = fmaxf(fmaxf(sacc[0][r], sacc[1][r]), fmaxf(sacc[2][r], sacc[3][r]));
            mx = fmaxf(mx, __shfl_xor(mx, 1));
            mx = fmaxf(mx, __shfl_xor(mx, 2));
            mx = fmaxf(mx, __shfl_xor(mx, 4));
            mx = fmaxf(mx, __shfl_xor(mx, 8));
            float mnew = fmaxf(m_i[r], mx);
            float alpha = __expf(m_i[r] - mnew);
            m_i[r] = mnew;
            float rs = 0.f;
#pragma unroll
            for (int nt = 0; nt < 4; ++nt) {
                float p = __expf(sacc[nt][r] - mnew);
                sacc[nt][r] = p;
                rs += p;
            }
            rs += __shfl_xor(rs, 1);
            rs += __shfl_xor(rs, 2);
            rs += __shfl_xor(rs, 4);
            rs += __shfl_xor(rs, 8);
            l_i[r] = l_i[r] * alpha + rs;
#pragma unroll
            for (int d8 = 0; d8 < 8; ++d8) o[d8][r] *= alpha;
        }

#pragma unroll
        for (int r = 0; r < 4; ++r)
#pragma unroll
            for (int nt = 0; nt < 4; ++nt)
                Psb[wave * 16 * PS_LD + (quad * 4 + r) * PS_LD + nt * 16 + l16] = (bf16_t)sacc[nt][r];

#pragma unroll
        for (int ks2 = 0; ks2 < 2; ++ks2) {
            bf16x8 a = *(const bf16x8*)&Psb[wave * 16 * PS_LD + l16 * PS_LD + ks2 * 32 + quad * 8];
#pragma unroll
            for (int d8 = 0; d8 < 8; ++d8) {
                int rw = d8 * 16 + l16;
                bf16x8 b = *(const bf16x8*)&Vts[rw * 64 + (((ks2 * 4 + quad) ^ xsw)) * 8];
                o[d8] = __builtin_amdgcn_mfma_f32_16x16x32_bf16(a, b, o[d8], 0, 0, 0);
            }
        }
    }

#pragma unroll
    for (int r = 0; r < 4; ++r) {
        float inv = 1.0f / l_i[r];
        size_t rowoff = (size_t)(t0 + wave * 16 + quad * 4 + r) * 2048 + h * HD;
#pragma unroll
        for (int d8 = 0; d8 < 8; ++d8)
            cxb[rowoff + d8 * 16 + l16] = (bf16_t)(o[d8][r] * inv);
    }
}

// ---------------------------------------------------------------------------
// Gated global low-rank branch (early-exit when gate==0); bf16 RMW into cxb
// ---------------------------------------------------------------------------
__device__ __forceinline__ float block_reduce_max512(float v, float* red, int tid) {
    red[tid] = v; __syncthreads();
    for (int s = 256; s > 0; s >>= 1) {
        if (tid < s) red[tid] = fmaxf(red[tid], red[tid + s]);
        __syncthreads();
    }
    float r = red[0]; __syncthreads();
    return r;
}
__device__ __forceinline__ float block_reduce_sum512(float v, float* red, int tid) {
    red[tid] = v; __syncthreads();
    for (int s = 256; s > 0; s >>= 1) {
        if (tid < s) red[tid] = red[tid] + red[tid + s];
        __syncthreads();
    }
    float r = red[0]; __syncthreads();
    return r;
}

__global__ __launch_bounds__(512)
void global_attn_kernel(bf16_t* __restrict__ cxb, const float* __restrict__ kr,
                        const float* __restrict__ vr, const bf16_t* __restrict__ qr,
                        const float* __restrict__ uo, const float* __restrict__ gate) {
    const int t = blockIdx.x, h = blockIdx.y;
    if (gate[t] <= 0.5f) return;

    __shared__ float qrs[64];
    __shared__ float red[512];
    __shared__ float cgr[64];
    __shared__ float sg[2048];
    const int tid = threadIdx.x;

    if (tid < 64) qrs[tid] = (float)qr[((size_t)h * T_LEN + t) * RANK + tid];
    __syncthreads();

    const float* krh = kr + (size_t)h * T_LEN * RANK;
    const float* vrh = vr + (size_t)h * T_LEN * RANK;
    float lmax = -INFINITY;
    for (int s = tid; s < T_LEN; s += 512) {
        const float* krr = krh + (size_t)s * RANK;
        float acc = 0.f;
#pragma unroll
        for (int r = 0; r < RANK; r += 4) {
            float4 k4 = *(const float4*)(krr + r);
            acc += qrs[r] * k4.x + qrs[r + 1] * k4.y + qrs[r + 2] * k4.z + qrs[r + 3] * k4.w;
        }
        float sc = acc * SCALE_G;
        sg[s] = sc;
        lmax = fmaxf(lmax, sc);
    }
    float gmx = block_reduce_max512(lmax, red, tid);
    float lsum = 0.f;
    for (int s = tid; s < T_LEN; s += 512) {
        float pp = expf(sg[s] - gmx);
        sg[s] = pp;
        lsum += pp;
    }
    float gsum = block_reduce_sum512(lsum, red, tid);

    {
        const int r = tid & 63, part = tid >> 6;
        float pacc = 0.f;
        for (int s = part; s < T_LEN; s += 8) pacc += sg[s] * vrh[(size_t)s * RANK + r];
        red[tid] = pacc;
        __syncthreads();
        if (tid < 64) {
            float c = 0.f;
#pragma unroll
            for (int pp = 0; pp < 8; ++pp) c += red[pp * 64 + tid];
            cgr[tid] = c / gsum;
        }
        __syncthreads();
    }

    if (tid < 128) {
        float cg = 0.f;
#pragma unroll
        for (int r = 0; r < RANK; ++r) cg += cgr[r] * uo[tid * RANK + r];
        size_t off = (size_t)t * 2048 + h * HD + tid;
        cxb[off] = (bf16_t)((float)cxb[off] + cg);
    }
}

// ---------------------------------------------------------------------------
extern "C" void kernel_launch(void* const* d_in, const int* in_sizes, int n_in,
                              void* d_out, int out_size, void* d_ws, size_t ws_size,
                              hipStream_t stream) {
    const float* x     = (const float*)d_in[0];
    const float* w_qkv = (const float*)d_in[1];
    const float* w_o   = (const float*)d_in[2];
    const float* pk    = (const float*)d_in[3];
    const float* pv    = (const float*)d_in[4];
    const float* uo    = (const float*)d_in[5];
    const float* w1    = (const float*)d_in[6];
    const float* w2    = (const float*)d_in[7];
    float* out = (float*)d_out;

    // Workspace layout (floats), lifetime-aliased (~88 MB):
    float* ws = (float*)d_ws;
    float* qkv   = ws;                        // 12,582,912 f: bf16 overlay rows
                                              //  q bf16 | K bf16 | wo bf16 | V bf16
    float* hinfo = qkv + (size_t)12582912;    // 1,048,576 f: rope tab, later qr bf16
    float* gatep = hinfo + (size_t)1048576;   // 2048 f
    bf16_t* xb   = (bf16_t*)(gatep + 2048);   // x_hi bf16 (later ctx bf16)
    float* wqbf  = gatep + 2048 + 2097152;    // 6,291,456 f region:
    bf16_t* wqb  = (bf16_t*)wqbf;             //   w_qkv bf16 (entire region)
    float* krp   = wqbf;                      //   later: kr
    float* vrp   = wqbf + (size_t)2097152;    //   later: vr
    float* tabp  = hinfo;                     // rope tables (dead before qr)
    bf16_t* qrp  = (bf16_t*)hinfo;            // qr bf16 (written by attn_fused)
    bf16_t* cxb  = xb;                        // ctx bf16
    bf16_t* qkvb = (bf16_t*)qkv;              // bf16 overlay view of qkv rows
    bf16_t* wob  = qkvb + WO_OFF;             // w_o bf16, row stride ROW_BF
    // d_out doubles as scratch until gemm_ctx_wo overwrites it:
    bf16_t* vtp  = (bf16_t*)d_out;            // V^T [16][128][2048] bf16 (8.39 MB)
    float* ipart = (float*)(vtp + (size_t)16 * 128 * 2048);  // 2x2048x512 f (8.39 MB)

    // 1) merged prep: x->bf16, w_qkv->bf16, rope tables
    prep_kernel<<<8704, 256, 0, stream>>>(x, xb, w_qkv, wqb, tabp);
    // 2) MERGED: info MLP + qkv GEMM v4 (fused RoPE, V overlay + V^T) + w_o->bf16
    gemm_qkv_rope<<<2944, 256, 0, stream>>>(xb, wqb, qkvb, vtp, tabp, w_o, x, w1, ipart);
    // 3) MERGED: local attention [0,512) + kvr [512,1024) + gate [1024,1536)
    attn_fused<<<1536, 256, 0, stream>>>(qkvb, vtp, cxb, pk, pv, krp, vrp, qrp,
                                         ipart, w2, gatep);
    // 4) gated global branch (bf16 RMW into cxb)
    global_attn_kernel<<<dim3(T_LEN, NH), 512, 0, stream>>>(cxb, krp, vrp, qrp, uo, gatep);
    // 5) out = ctx @ w_o^T  (v4 pipelined, 128x64 tiles, 2 blocks/CU)
    gemm_ctx_wo<<<512, 256, 0, stream>>>(cxb, wob, out);
}